// Round 5
// baseline (3834.485 us; speedup 1.0000x reference)
//
#include <hip/hip_runtime.h>

#define TT    1024   // timesteps
#define BATCH 2048
#define NI    6      // input dim
#define NH    38     // hidden
#define NCLS  8      // classes
#define NB    4      // batches per block  -> grid 512 = 2 blocks/CU
#define HP    48     // padded row: h(38) pad(2) x(6) pad(2)  (h2: cols 38..47 = 0)
#define XOFF  40     // x offset inside h1 row
#define BLK   512

typedef float4 F4;

__device__ __forceinline__ float fsig(float v)  { return __fdividef(1.0f, 1.0f + __expf(-v)); }
__device__ __forceinline__ float ftanh(float v) { return 1.0f - __fdividef(2.0f, 1.0f + __expf(2.0f * v)); }

// augmented L1 weight element: cols 0..37 = Whh0, cols 40..45 = Wih0, else 0
__device__ __forceinline__ float augw(const float* Whh, const float* Wih, int row, int c) {
    if (c < NH) return Whh[row * NH + c];
    if (c >= XOFF && c < XOFF + NI) return Wih[row * NI + (c - XOFF)];
    return 0.0f;
}
__device__ __forceinline__ F4 aug4(const float* Whh, const float* Wih, int row, int c) {
    F4 v; v.x = augw(Whh, Wih, row, c + 0); v.y = augw(Whh, Wih, row, c + 1);
    v.z = augw(Whh, Wih, row, c + 2); v.w = augw(Whh, Wih, row, c + 3); return v;
}
// zero-padded L2 weight element: cols 0..37 = W, cols 38..47 = 0
__device__ __forceinline__ F4 ldp4(const float* W, int row, int c) {
    F4 v; v.x = (c + 0 < NH) ? W[row * NH + c + 0] : 0.0f;
          v.y = (c + 1 < NH) ? W[row * NH + c + 1] : 0.0f;
          v.z = (c + 2 < NH) ? W[row * NH + c + 2] : 0.0f;
          v.w = (c + 3 < NH) ? W[row * NH + c + 3] : 0.0f; return v;
}

// ---------- unified macro-unrolled body: ONE shared weight set, per-batch rounds ----

#define GDOT(ACC, WA, WB, WC) \
    ACC += WA.x*hA.x; ACC += WA.y*hA.y; ACC += WA.z*hA.z; ACC += WA.w*hA.w; \
    ACC += WB.x*hB.x; ACC += WB.y*hB.y; ACC += WB.z*hB.z; ACC += WB.w*hB.w; \
    ACC += WC.x*hC.x; ACC += WC.y*hC.y; ACC += WC.z*hC.z; ACC += WC.w*hC.w;

// one batch round: dot over this lane's 12-col slice, combine across the lane
// group, keep result only on the owning lane (own = sub&3). 4 accs live, not 16.
#define ROUND(bb, HB) { \
    const float* hr = (HB) + (bb) * HP; \
    const F4 hA = *(const F4*)(hr + 0); \
    const F4 hB = *(const F4*)(hr + 4); \
    const F4 hC = *(const F4*)(hr + 8); \
    float t0 = 0.f, t1 = 0.f, t2 = 0.f, t3 = 0.f; \
    GDOT(t0, w00, w01, w02) GDOT(t1, w10, w11, w12) \
    GDOT(t2, w20, w21, w22) GDOT(t3, w30, w31, w32) \
    t0 += __shfl_xor(t0, 1); t1 += __shfl_xor(t1, 1); \
    t2 += __shfl_xor(t2, 1); t3 += __shfl_xor(t3, 1); \
    t0 += __shfl_xor(t0, 2); t1 += __shfl_xor(t1, 2); \
    t2 += __shfl_xor(t2, 2); t3 += __shfl_xor(t3, 2); \
    if (isL2) { \
        t0 += __shfl_xor(t0, 4); t1 += __shfl_xor(t1, 4); \
        t2 += __shfl_xor(t2, 4); t3 += __shfl_xor(t3, 4); \
    } \
    pv0 = (own == (bb)) ? t0 : pv0;  pv1 = (own == (bb)) ? t1 : pv1; \
    pv2 = (own == (bb)) ? t2 : pv2;  pv3 = (own == (bb)) ? t3 : pv3; }

#define BODY(HB, WR, WEN) { \
    float pv0 = 0.f, pv1 = 0.f, pv2 = 0.f, pv3 = 0.f; \
    ROUND(0, HB) ROUND(1, HB) ROUND(2, HB) ROUND(3, HB) \
    const float ig = fsig(bs0 + pv0), fg = fsig(bs1 + pv1); \
    const float gg = ftanh(bs2 + pv2), og = fsig(bs3 + pv3); \
    const float cc = fg * cl0 + ig * gg; cl0 = cc; \
    if (WEN) *(WR) = og * ftanh(cc); }

// One pipeline iteration. PF load issued FIRST (T14: issue-early / write-late).
#define ITER(L1GO, L2GO, TNX, HB, WR, PW) { \
    const int tnx_ = (TNX); \
    const bool pfgo_ = isPF && (tnx_ < TT); \
    float pfv_ = 0.0f; \
    if (pfgo_) pfv_ = xg[(size_t)tnx_ * NI]; \
    if (isL1) { if (L1GO) BODY(HB, WR, true) } \
    else if (isL2) { if (L2GO) BODY(HB, WR, (sub < 4)) } \
    if (pfgo_) *(PW) = pfv_; \
    __syncthreads(); }

// Role layout (8 waves / 512 threads), skewed pipeline, one barrier/iter:
//   tid   0..151 : L1. sub=tid&3 (12-col slice of augmented 48-col row), u=tid>>2.
//                  Owns batch `sub`. shfl_xor(1,2). Writes h1buf[cur][sub][u].
//   tid 152..175 : x prefetch, 1 element each (into h1buf[cur] x-columns).
//   tid 192..495 : L2. m=tid-192, sub=m&7, u=m>>3. subs 0-3: Wih1 12-col slices
//                  (reads h1buf[prv]); subs 4-7: Whh1 (reads h2buf[cur]).
//                  shfl_xor(1,2) + xor(4). Owns batch sub&3; sub<4 writes
//                  h2buf[prv][sub&3][u].
// Iter i: L1 -> h1(i), L2 -> h2(i-1). Loop i=0..TT. Final h2(TT-1) in h2buf[1].
//
// KEY (R3/R4 post-mortem): L1 and L2 load weights into the SAME named F4 set.
// Splitting names (R3 w* vs u*) made both sets live in every thread under
// divergent flow -> 80 B/thread scratch spill (WRITE_SIZE 21 MB). Shared names
// + per-batch rounds cap peak live at ~80 floats -> fits the ~80-reg budget
// the allocator grants at launch_bounds(512,2) (R2 evidence: VGPR=80, no spill).

__global__ __launch_bounds__(BLK, 2) void lstm2_kernel(
    const float* __restrict__ x,
    const float* __restrict__ Wih0, const float* __restrict__ Whh0, const float* __restrict__ b0,
    const float* __restrict__ Wih1, const float* __restrict__ Whh1, const float* __restrict__ b1,
    const float* __restrict__ Wc,   const float* __restrict__ bc,
    float* __restrict__ out)
{
    __shared__ __align__(16) float h1buf[2][NB][HP];
    __shared__ __align__(16) float h2buf[2][NB][HP];

    const int tid   = threadIdx.x;
    const int bbase = blockIdx.x * NB;

    // zero both state buffers (pads + x slots start at 0)
    for (int idx = tid; idx < 2 * NB * HP; idx += BLK) {
        (&h1buf[0][0][0])[idx] = 0.0f;
        (&h2buf[0][0][0])[idx] = 0.0f;
    }
    __syncthreads();
    // x(0) into slot 1 (iter 0 reads prv=1)
    if (tid < NB * NI) {
        const int b = tid / NI, j = tid % NI;
        h1buf[1][b][XOFF + j] = x[(size_t)(bbase + b) * TT * NI + j];
    }

    const bool isL1 = (tid < 152);
    const bool isPF = (tid >= 152) && (tid < 152 + NB * NI);
    const bool isL2 = (tid >= 192) && (tid < 192 + 304);

    int sub = 0, u = 0;
    if (isL1)      { sub = tid & 3; u = tid >> 2; }
    else if (isL2) { const int m = tid - 192; sub = m & 7; u = m >> 3; }
    const int own = sub & 3;

    // ---- ONE shared named weight set: 12 F4 = 48 floats, both roles ----
    F4 w00, w01, w02, w10, w11, w12, w20, w21, w22, w30, w31, w32;
    {
        const F4 z = {0.f, 0.f, 0.f, 0.f};
        w00=z; w01=z; w02=z; w10=z; w11=z; w12=z;
        w20=z; w21=z; w22=z; w30=z; w31=z; w32=z;
    }
    float bs0 = 0.f, bs1 = 0.f, bs2 = 0.f, bs3 = 0.f;

    const float *hb0 = nullptr, *hb1 = nullptr, *xg = nullptr;
    float *wr0 = nullptr, *wr1 = nullptr, *pw0 = nullptr, *pw1 = nullptr;

    if (isL1) {
        const int c = 12 * sub;
        w00 = aug4(Whh0, Wih0, u + 0*NH, c); w01 = aug4(Whh0, Wih0, u + 0*NH, c + 4);
        w02 = aug4(Whh0, Wih0, u + 0*NH, c + 8);
        w10 = aug4(Whh0, Wih0, u + 1*NH, c); w11 = aug4(Whh0, Wih0, u + 1*NH, c + 4);
        w12 = aug4(Whh0, Wih0, u + 1*NH, c + 8);
        w20 = aug4(Whh0, Wih0, u + 2*NH, c); w21 = aug4(Whh0, Wih0, u + 2*NH, c + 4);
        w22 = aug4(Whh0, Wih0, u + 2*NH, c + 8);
        w30 = aug4(Whh0, Wih0, u + 3*NH, c); w31 = aug4(Whh0, Wih0, u + 3*NH, c + 4);
        w32 = aug4(Whh0, Wih0, u + 3*NH, c + 8);
        bs0 = b0[u]; bs1 = b0[u + NH]; bs2 = b0[u + 2*NH]; bs3 = b0[u + 3*NH];
        hb0 = &h1buf[1][0][c];         // parity 0 reads PRV=1
        hb1 = &h1buf[0][0][c];
        wr0 = &h1buf[0][sub][u];       // parity 0 writes CUR=0
        wr1 = &h1buf[1][sub][u];
    } else if (isL2) {
        const float* Wm = (sub < 4) ? Wih1 : Whh1;
        const int c = 12 * own;
        w00 = ldp4(Wm, u + 0*NH, c); w01 = ldp4(Wm, u + 0*NH, c + 4); w02 = ldp4(Wm, u + 0*NH, c + 8);
        w10 = ldp4(Wm, u + 1*NH, c); w11 = ldp4(Wm, u + 1*NH, c + 4); w12 = ldp4(Wm, u + 1*NH, c + 8);
        w20 = ldp4(Wm, u + 2*NH, c); w21 = ldp4(Wm, u + 2*NH, c + 4); w22 = ldp4(Wm, u + 2*NH, c + 8);
        w30 = ldp4(Wm, u + 3*NH, c); w31 = ldp4(Wm, u + 3*NH, c + 4); w32 = ldp4(Wm, u + 3*NH, c + 8);
        bs0 = b1[u]; bs1 = b1[u + NH]; bs2 = b1[u + 2*NH]; bs3 = b1[u + 3*NH];
        if (sub < 4) { hb0 = &h1buf[1][0][c]; hb1 = &h1buf[0][0][c]; }   // Wih1 side: h1(i-1)
        else         { hb0 = &h2buf[0][0][c]; hb1 = &h2buf[1][0][c]; }   // Whh1 side: h2(i-2)
        wr0 = &h2buf[1][own][u];       // parity 0 writes PRV=1
        wr1 = &h2buf[0][own][u];
    } else if (isPF) {
        const int e = tid - 152, b = e / NI, j = e % NI;
        xg  = x + (size_t)(bbase + b) * TT * NI + j;
        pw0 = &h1buf[0][b][XOFF + j];  // parity 0 writes CUR=0 (consumed next iter)
        pw1 = &h1buf[1][b][XOFF + j];
    }

    float cl0 = 0.0f;   // cell state for the owned batch

    __syncthreads();

    // iter 0: parity 0 (CUR=0, PRV=1): L1 only; PF x(1) -> h1buf[0]
    ITER(true, false, 1, hb0, wr0, pw0)

    // pairs (i, i+1) for i = 1,3,...,1023  -> iterations 1..1024
    #pragma unroll 1
    for (int i = 1; i < TT; i += 2) {
        ITER(true, true, i + 1, hb1, wr1, pw1)            // parity 1
        ITER(i + 1 < TT, true, i + 2, hb0, wr0, pw0)      // parity 0
    }

    // epilogue: out = h2(TT-1) @ Wc.T + bc ; final h2 in h2buf[1]
    if (tid < NB * NCLS) {
        const int b = tid >> 3, c = tid & 7;
        float acc = bc[c];
        #pragma unroll
        for (int k = 0; k < NH; ++k) acc += Wc[c * NH + k] * h2buf[1][b][k];
        out[(size_t)(bbase + b) * NCLS + c] = acc;
    }
}

extern "C" void kernel_launch(void* const* d_in, const int* in_sizes, int n_in,
                              void* d_out, int out_size, void* d_ws, size_t ws_size,
                              hipStream_t stream) {
    const float* x    = (const float*)d_in[0];
    const float* Wih0 = (const float*)d_in[1];
    const float* Whh0 = (const float*)d_in[2];
    const float* b0   = (const float*)d_in[3];
    const float* Wih1 = (const float*)d_in[4];
    const float* Whh1 = (const float*)d_in[5];
    const float* b1   = (const float*)d_in[6];
    const float* Wc   = (const float*)d_in[7];
    const float* bc   = (const float*)d_in[8];
    float* out = (float*)d_out;

    dim3 grid(BATCH / NB);
    dim3 block(BLK);
    hipLaunchKernelGGL(lstm2_kernel, grid, block, 0, stream,
                       x, Wih0, Whh0, b0, Wih1, Whh1, b1, Wc, bc, out);
}

// Round 6
// 2178.806 us; speedup vs baseline: 1.7599x; 1.7599x over previous
//
#include <hip/hip_runtime.h>

#define TT    1024   // timesteps
#define BATCH 2048
#define NI    6      // input dim
#define NH    38     // hidden
#define NCLS  8      // classes
#define NB    8      // batches per block  -> grid 256 = exactly 1 block/CU
#define HP1   48     // h1 row: h(38) pad(2) x(6) pad(2)
#define HP2   40     // h2 row: h(38) pad(2)
#define XOFF  40     // x offset inside h1 row
#define BLK   512

typedef float4 F4;

__device__ __forceinline__ float fsig(float v)  { return __fdividef(1.0f, 1.0f + __expf(-v)); }
__device__ __forceinline__ float ftanh(float v) { return 1.0f - __fdividef(2.0f, 1.0f + __expf(2.0f * v)); }

// augmented L1 weight element: cols 0..37 = Whh0, cols 40..45 = Wih0, else 0
__device__ __forceinline__ float augw(const float* Whh, const float* Wih, int row, int c) {
    if (c < NH) return Whh[row * NH + c];
    if (c >= XOFF && c < XOFF + NI) return Wih[row * NI + (c - XOFF)];
    return 0.0f;
}
__device__ __forceinline__ F4 aug4(const float* Whh, const float* Wih, int row, int c) {
    F4 v; v.x = augw(Whh, Wih, row, c + 0); v.y = augw(Whh, Wih, row, c + 1);
    v.z = augw(Whh, Wih, row, c + 2); v.w = augw(Whh, Wih, row, c + 3); return v;
}
// zero-padded L2 weight element: cols 0..37 = W, else 0
__device__ __forceinline__ F4 ldp4(const float* W, int row, int c) {
    F4 v; v.x = (c + 0 < NH) ? W[row * NH + c + 0] : 0.0f;
          v.y = (c + 1 < NH) ? W[row * NH + c + 1] : 0.0f;
          v.z = (c + 2 < NH) ? W[row * NH + c + 2] : 0.0f;
          v.w = (c + 3 < NH) ? W[row * NH + c + 3] : 0.0f; return v;
}

#define FMA4(T, W, H) T += W.x*H.x; T += W.y*H.y; T += W.z*H.z; T += W.w*H.w;

// ---- L1: 6-F4 dot (24 cols of augmented row), pair combine, keep own batch ----
// bb -> (OWN, P): 0->(0,A) 1->(0,B) 2->(1,A) 3->(1,B)
#define L1ROUND(bb, OWN, P, HB) { \
    const float* hr = (HB) + (bb) * HP1; \
    const F4 hv0 = *(const F4*)(hr + 0),  hv1 = *(const F4*)(hr + 4); \
    const F4 hv2 = *(const F4*)(hr + 8),  hv3 = *(const F4*)(hr + 12); \
    const F4 hv4 = *(const F4*)(hr + 16), hv5 = *(const F4*)(hr + 20); \
    float t0 = 0.f, t1 = 0.f, t2 = 0.f, t3 = 0.f; \
    FMA4(t0, wa0, hv0) FMA4(t0, wa1, hv1) FMA4(t0, wa2, hv2) \
    FMA4(t0, wa3, hv3) FMA4(t0, wa4, hv4) FMA4(t0, wa5, hv5) \
    FMA4(t1, wb0, hv0) FMA4(t1, wb1, hv1) FMA4(t1, wb2, hv2) \
    FMA4(t1, wb3, hv3) FMA4(t1, wb4, hv4) FMA4(t1, wb5, hv5) \
    FMA4(t2, wc0, hv0) FMA4(t2, wc1, hv1) FMA4(t2, wc2, hv2) \
    FMA4(t2, wc3, hv3) FMA4(t2, wc4, hv4) FMA4(t2, wc5, hv5) \
    FMA4(t3, wd0, hv0) FMA4(t3, wd1, hv1) FMA4(t3, wd2, hv2) \
    FMA4(t3, wd3, hv3) FMA4(t3, wd4, hv4) FMA4(t3, wd5, hv5) \
    t0 += __shfl_xor(t0, 1); t1 += __shfl_xor(t1, 1); \
    t2 += __shfl_xor(t2, 1); t3 += __shfl_xor(t3, 1); \
    pv##P##0 = (sub == (OWN)) ? t0 : pv##P##0; \
    pv##P##1 = (sub == (OWN)) ? t1 : pv##P##1; \
    pv##P##2 = (sub == (OWN)) ? t2 : pv##P##2; \
    pv##P##3 = (sub == (OWN)) ? t3 : pv##P##3; }

// ---- L2: 5-F4 dot (20 cols of [Wih1|Whh1] space), quad combine, keep own batch ----
#define L2ROUND(bb, HB) { \
    const float* hr = (HB) + (bb) * l2str; \
    const F4 hv0 = *(const F4*)(hr + 0),  hv1 = *(const F4*)(hr + 4); \
    const F4 hv2 = *(const F4*)(hr + 8),  hv3 = *(const F4*)(hr + 12); \
    const F4 hv4 = *(const F4*)(hr + 16); \
    float t0 = 0.f, t1 = 0.f, t2 = 0.f, t3 = 0.f; \
    FMA4(t0, wa0, hv0) FMA4(t0, wa1, hv1) FMA4(t0, wa2, hv2) \
    FMA4(t0, wa3, hv3) FMA4(t0, wa4, hv4) \
    FMA4(t1, wb0, hv0) FMA4(t1, wb1, hv1) FMA4(t1, wb2, hv2) \
    FMA4(t1, wb3, hv3) FMA4(t1, wb4, hv4) \
    FMA4(t2, wc0, hv0) FMA4(t2, wc1, hv1) FMA4(t2, wc2, hv2) \
    FMA4(t2, wc3, hv3) FMA4(t2, wc4, hv4) \
    FMA4(t3, wd0, hv0) FMA4(t3, wd1, hv1) FMA4(t3, wd2, hv2) \
    FMA4(t3, wd3, hv3) FMA4(t3, wd4, hv4) \
    t0 += __shfl_xor(t0, 1); t1 += __shfl_xor(t1, 1); \
    t2 += __shfl_xor(t2, 1); t3 += __shfl_xor(t3, 1); \
    t0 += __shfl_xor(t0, 2); t1 += __shfl_xor(t1, 2); \
    t2 += __shfl_xor(t2, 2); t3 += __shfl_xor(t3, 2); \
    pvA0 = (sub == (bb)) ? t0 : pvA0;  pvA1 = (sub == (bb)) ? t1 : pvA1; \
    pvA2 = (sub == (bb)) ? t2 : pvA2;  pvA3 = (sub == (bb)) ? t3 : pvA3; }

#define PWSTEP(P0, P1, P2, P3, CL, WP) { \
    const float ig = fsig(bs0 + P0), fg = fsig(bs1 + P1); \
    const float gg = ftanh(bs2 + P2), og = fsig(bs3 + P3); \
    const float cc = fg * CL + ig * gg; CL = cc; \
    *(WP) = og * ftanh(cc); }

#define L1BODY(HB, WR) { \
    float pvA0=0.f,pvA1=0.f,pvA2=0.f,pvA3=0.f, pvB0=0.f,pvB1=0.f,pvB2=0.f,pvB3=0.f; \
    L1ROUND(0, 0, A, HB) L1ROUND(1, 0, B, HB) L1ROUND(2, 1, A, HB) L1ROUND(3, 1, B, HB) \
    PWSTEP(pvA0, pvA1, pvA2, pvA3, cl0, WR) \
    PWSTEP(pvB0, pvB1, pvB2, pvB3, cl1, (WR) + HP1) }

#define L2BODY(HB, WR) { \
    float pvA0=0.f,pvA1=0.f,pvA2=0.f,pvA3=0.f; \
    L2ROUND(0, HB) L2ROUND(1, HB) L2ROUND(2, HB) L2ROUND(3, HB) \
    PWSTEP(pvA0, pvA1, pvA2, pvA3, cl0, WR) }

// One pipeline iteration. PF load issued FIRST (issue-early / write-late).
#define ITER(L1GO, L2GO, TNX, HB, WR, PW) { \
    const int tnx_ = (TNX); \
    const bool pfgo_ = isPF && (tnx_ < TT); \
    float pfv_ = 0.0f; \
    if (pfgo_) pfv_ = xg[(size_t)tnx_ * NI]; \
    if (isL1) { if (L1GO) L1BODY(HB, WR) } \
    else if (isL2) { if (L2GO) L2BODY(HB, WR) } \
    if (pfgo_) *(PW) = pfv_; \
    __syncthreads(); }

// Role layout (8 waves / 512 threads), skewed pipeline, one barrier/iter:
//   tid   0..151 : L1. pair k=tid>>1: u=k%38, bg=k/38 (b0i=4bg); sub=tid&1 ->
//                  24-col slice of augmented 48-col row [h(38)|pad|x(6)|pad].
//                  96 weight floats. 4 rounds x (96 FMA + xor1). Owns batches
//                  b0i+2sub+{0,1}. Writes h1buf[cur][own][u].
//   tid 152..199 : x prefetch, 1 element each, into h1buf[cur] x-cols.
//   tid 200..207 : idle.
//   tid 208..511 : L2. m=tid-208: quad k=m>>2 (u=k%38, bg, b0i=4bg), sub=m&3 ->
//                  20-col slice of [Wih1(40-pad) | Whh1(40-pad)]. side=sub>>1
//                  (0: reads h1(i-1), 1: reads h2(i-2)), half=sub&1. 80 weight
//                  floats. 4 rounds x (80 FMA + xor1 + xor2). Owns batch
//                  b0i+sub. Writes h2buf[wslot][own][u].
// Iter i: L1 -> h1(i), L2 -> h2(i-1). Loop i=0..TT. Final h2(TT-1) in h2buf[1].
//
// LDS PAD (the round-6 lever): rounds 1-5 showed the backend budgets VGPRs
// from the LDS-derived occupancy bound (38K->104, 10.7K->112, 5.6K->80,
// 3K->64 regs), ignoring launch_bounds/waves_per_eu. 88 KB static LDS ->
// 1 block/CU -> 2 waves/EU -> 256-reg budget, so the ~160-float live set
// (96 weights + h-frags + partials) stays fully register-resident: no spill,
// no remat reloads. Grid=256 = 1 block/CU exactly, so the pad wastes nothing.

__global__ __launch_bounds__(BLK, 2) void lstm2_kernel(
    const float* __restrict__ x,
    const float* __restrict__ Wih0, const float* __restrict__ Whh0, const float* __restrict__ b0,
    const float* __restrict__ Wih1, const float* __restrict__ Whh1, const float* __restrict__ b1,
    const float* __restrict__ Wc,   const float* __restrict__ bc,
    float* __restrict__ out)
{
    __shared__ __align__(16) float h1buf[2][NB][HP1];   // 3072 B
    __shared__ __align__(16) float h2buf[2][NB][HP2];   // 2560 B
    __shared__ float ldspad[20736];                     // 82944 B -> total ~88.5 KB

    const int tid   = threadIdx.x;
    const int bbase = blockIdx.x * NB;

    // keep the pad alive (runtime-false guard; inputs are ~N(0,0.16))
    if (bc[0] > 3.0e38f) ldspad[tid] = x[tid];

    // zero both state buffers (pads + x slots start at 0)
    for (int idx = tid; idx < 2 * NB * HP1; idx += BLK) (&h1buf[0][0][0])[idx] = 0.0f;
    for (int idx = tid; idx < 2 * NB * HP2; idx += BLK) (&h2buf[0][0][0])[idx] = 0.0f;
    __syncthreads();
    // x(0) into slot 1 x-cols (iter 0 reads prv=1)
    if (tid < NB * NI) {
        const int b = tid / NI, j = tid % NI;
        h1buf[1][b][XOFF + j] = x[(size_t)(bbase + b) * TT * NI + j];
    }

    const bool isL1 = (tid < 152);
    const bool isPF = (tid >= 152) && (tid < 152 + NB * NI);
    const bool isL2 = (tid >= 208);

    int sub = 0, u = 0, b0i = 0;
    if (isL1)      { const int k = tid >> 1;  sub = tid & 1; u = k % NH; b0i = (k / NH) * 4; }
    else if (isL2) { const int m = tid - 208; const int k = m >> 2;
                     sub = m & 3; u = k % NH; b0i = (k / NH) * 4; }

    // ---- ONE shared named weight set: 24 F4 (L1 uses all, L2 first 20) ----
    F4 wa0,wa1,wa2,wa3,wa4,wa5, wb0,wb1,wb2,wb3,wb4,wb5;
    F4 wc0,wc1,wc2,wc3,wc4,wc5, wd0,wd1,wd2,wd3,wd4,wd5;
    {
        const F4 z = {0.f,0.f,0.f,0.f};
        wa0=z;wa1=z;wa2=z;wa3=z;wa4=z;wa5=z; wb0=z;wb1=z;wb2=z;wb3=z;wb4=z;wb5=z;
        wc0=z;wc1=z;wc2=z;wc3=z;wc4=z;wc5=z; wd0=z;wd1=z;wd2=z;wd3=z;wd4=z;wd5=z;
    }
    float bs0=0.f, bs1=0.f, bs2=0.f, bs3=0.f;
    int l2str = 0;

    const float *hb0 = nullptr, *hb1 = nullptr, *xg = nullptr;
    float *wr0 = nullptr, *wr1 = nullptr, *pw0 = nullptr, *pw1 = nullptr;

    if (isL1) {
        const int c = 24 * sub;
        wa0=aug4(Whh0,Wih0,u+0*NH,c);   wa1=aug4(Whh0,Wih0,u+0*NH,c+4);
        wa2=aug4(Whh0,Wih0,u+0*NH,c+8); wa3=aug4(Whh0,Wih0,u+0*NH,c+12);
        wa4=aug4(Whh0,Wih0,u+0*NH,c+16);wa5=aug4(Whh0,Wih0,u+0*NH,c+20);
        wb0=aug4(Whh0,Wih0,u+1*NH,c);   wb1=aug4(Whh0,Wih0,u+1*NH,c+4);
        wb2=aug4(Whh0,Wih0,u+1*NH,c+8); wb3=aug4(Whh0,Wih0,u+1*NH,c+12);
        wb4=aug4(Whh0,Wih0,u+1*NH,c+16);wb5=aug4(Whh0,Wih0,u+1*NH,c+20);
        wc0=aug4(Whh0,Wih0,u+2*NH,c);   wc1=aug4(Whh0,Wih0,u+2*NH,c+4);
        wc2=aug4(Whh0,Wih0,u+2*NH,c+8); wc3=aug4(Whh0,Wih0,u+2*NH,c+12);
        wc4=aug4(Whh0,Wih0,u+2*NH,c+16);wc5=aug4(Whh0,Wih0,u+2*NH,c+20);
        wd0=aug4(Whh0,Wih0,u+3*NH,c);   wd1=aug4(Whh0,Wih0,u+3*NH,c+4);
        wd2=aug4(Whh0,Wih0,u+3*NH,c+8); wd3=aug4(Whh0,Wih0,u+3*NH,c+12);
        wd4=aug4(Whh0,Wih0,u+3*NH,c+16);wd5=aug4(Whh0,Wih0,u+3*NH,c+20);
        bs0=b0[u]; bs1=b0[u+NH]; bs2=b0[u+2*NH]; bs3=b0[u+3*NH];
        hb0 = &h1buf[1][b0i][c];            // parity0 reads PRV=1
        hb1 = &h1buf[0][b0i][c];
        wr0 = &h1buf[0][b0i + 2*sub][u];    // parity0 writes CUR=0 (2 rows)
        wr1 = &h1buf[1][b0i + 2*sub][u];
    } else if (isL2) {
        const int side = sub >> 1, half = sub & 1;
        const float* Wm = side ? Whh1 : Wih1;
        const int c = 20 * half;
        wa0=ldp4(Wm,u+0*NH,c); wa1=ldp4(Wm,u+0*NH,c+4); wa2=ldp4(Wm,u+0*NH,c+8);
        wa3=ldp4(Wm,u+0*NH,c+12); wa4=ldp4(Wm,u+0*NH,c+16);
        wb0=ldp4(Wm,u+1*NH,c); wb1=ldp4(Wm,u+1*NH,c+4); wb2=ldp4(Wm,u+1*NH,c+8);
        wb3=ldp4(Wm,u+1*NH,c+12); wb4=ldp4(Wm,u+1*NH,c+16);
        wc0=ldp4(Wm,u+2*NH,c); wc1=ldp4(Wm,u+2*NH,c+4); wc2=ldp4(Wm,u+2*NH,c+8);
        wc3=ldp4(Wm,u+2*NH,c+12); wc4=ldp4(Wm,u+2*NH,c+16);
        wd0=ldp4(Wm,u+3*NH,c); wd1=ldp4(Wm,u+3*NH,c+4); wd2=ldp4(Wm,u+3*NH,c+8);
        wd3=ldp4(Wm,u+3*NH,c+12); wd4=ldp4(Wm,u+3*NH,c+16);
        bs0=b1[u]; bs1=b1[u+NH]; bs2=b1[u+2*NH]; bs3=b1[u+3*NH];
        l2str = side ? HP2 : HP1;
        hb0 = side ? &h2buf[0][b0i][c] : &h1buf[1][b0i][c];   // parity0: h2(i-2) / h1(i-1)
        hb1 = side ? &h2buf[1][b0i][c] : &h1buf[0][b0i][c];
        wr0 = &h2buf[1][b0i + sub][u];      // parity0 writes PRV=1
        wr1 = &h2buf[0][b0i + sub][u];
    } else if (isPF) {
        const int e = tid - 152, b = e / NI, j = e % NI;
        xg  = x + (size_t)(bbase + b) * TT * NI + j;
        pw0 = &h1buf[0][b][XOFF + j];       // parity0 writes CUR=0 x-cols
        pw1 = &h1buf[1][b][XOFF + j];
    }

    float cl0 = 0.0f, cl1 = 0.0f;   // cell states (L1: 2 batches; L2: cl0)

    __syncthreads();

    // iter 0: parity0 (CUR=0, PRV=1): L1 only; PF x(1) -> h1buf[0]
    ITER(true, false, 1, hb0, wr0, pw0)

    // pairs (i, i+1) for i = 1,3,...,1023  -> iterations 1..1024
    #pragma unroll 1
    for (int i = 1; i < TT; i += 2) {
        ITER(true, true, i + 1, hb1, wr1, pw1)            // parity 1
        ITER(i + 1 < TT, true, i + 2, hb0, wr0, pw0)      // parity 0
    }

    // epilogue: out = h2(TT-1) @ Wc.T + bc ; final h2 in h2buf[1]
    if (tid < NB * NCLS) {
        const int b = tid >> 3, c = tid & 7;
        float acc = bc[c];
        #pragma unroll
        for (int k = 0; k < NH; ++k) acc += Wc[c * NH + k] * h2buf[1][b][k];
        out[(size_t)(bbase + b) * NCLS + c] = acc;
    }
    if (bc[0] > 3.0e38f) out[tid] = ldspad[BLK - tid];
}

extern "C" void kernel_launch(void* const* d_in, const int* in_sizes, int n_in,
                              void* d_out, int out_size, void* d_ws, size_t ws_size,
                              hipStream_t stream) {
    const float* x    = (const float*)d_in[0];
    const float* Wih0 = (const float*)d_in[1];
    const float* Whh0 = (const float*)d_in[2];
    const float* b0   = (const float*)d_in[3];
    const float* Wih1 = (const float*)d_in[4];
    const float* Whh1 = (const float*)d_in[5];
    const float* b1   = (const float*)d_in[6];
    const float* Wc   = (const float*)d_in[7];
    const float* bc   = (const float*)d_in[8];
    float* out = (float*)d_out;

    dim3 grid(BATCH / NB);
    dim3 block(BLK);
    hipLaunchKernelGGL(lstm2_kernel, grid, block, 0, stream,
                       x, Wih0, Whh0, b0, Wih1, Whh1, b1, Wc, bc, out);
}

// Round 7
// 1965.599 us; speedup vs baseline: 1.9508x; 1.1085x over previous
//
#include <hip/hip_runtime.h>

#define TT    1024   // timesteps
#define BATCH 2048
#define NI    6      // input dim
#define NH    38     // hidden
#define NCLS  8      // classes
#define NB    8      // batches per block  -> grid 256 = exactly 1 block/CU
#define HP1   48     // h1 row: h(38) pad(2) x(6) pad(2)
#define HP2   48     // h2 row padded to SAME stride -> literal slice offsets
#define XOFF  40     // x offset inside h1 row
#define BLK   512

typedef float4 F4;

__device__ __forceinline__ float fsig(float v)  { return __fdividef(1.0f, 1.0f + __expf(-v)); }
__device__ __forceinline__ float ftanh(float v) { return 1.0f - __fdividef(2.0f, 1.0f + __expf(2.0f * v)); }

// augmented L1 weight element: cols 0..37 = Whh0, cols 40..45 = Wih0, else 0
__device__ __forceinline__ float augw(const float* Whh, const float* Wih, int row, int c) {
    if (c < NH) return Whh[row * NH + c];
    if (c >= XOFF && c < XOFF + NI) return Wih[row * NI + (c - XOFF)];
    return 0.0f;
}
__device__ __forceinline__ F4 aug4(const float* Whh, const float* Wih, int row, int c) {
    F4 v; v.x = augw(Whh, Wih, row, c + 0); v.y = augw(Whh, Wih, row, c + 1);
    v.z = augw(Whh, Wih, row, c + 2); v.w = augw(Whh, Wih, row, c + 3); return v;
}
// zero-padded L2 weight element: cols 0..37 = W, else 0
__device__ __forceinline__ F4 ldp4(const float* W, int row, int c) {
    F4 v; v.x = (c + 0 < NH) ? W[row * NH + c + 0] : 0.0f;
          v.y = (c + 1 < NH) ? W[row * NH + c + 1] : 0.0f;
          v.z = (c + 2 < NH) ? W[row * NH + c + 2] : 0.0f;
          v.w = (c + 3 < NH) ? W[row * NH + c + 3] : 0.0f; return v;
}

// ---- DPP intra-quad butterfly add (no LDS pipe; quads are lane-aligned) ----
// quad_perm xor1 = [1,0,3,2] = 0xB1 ; xor2 = [2,3,0,1] = 0x4E
#define QX1(v) ((v) + __int_as_float(__builtin_amdgcn_mov_dpp(__float_as_int(v), 0xB1, 0xF, 0xF, true)))
#define QX2(v) ((v) + __int_as_float(__builtin_amdgcn_mov_dpp(__float_as_int(v), 0x4E, 0xF, 0xF, true)))

#define FMA4(T, W, H) T += W.x*H.x; T += W.y*H.y; T += W.z*H.z; T += W.w*H.w;

#define ACC16 \
    float a00=0.f,a01=0.f,a02=0.f,a03=0.f, a10=0.f,a11=0.f,a12=0.f,a13=0.f; \
    float a20=0.f,a21=0.f,a22=0.f,a23=0.f, a30=0.f,a31=0.f,a32=0.f,a33=0.f;

// k-outer slice: read 4 batches' h-F4 at this k, do 4x4 FMAs. Weight F4s
// wa#s..wd#s are each touched ONCE per step (amortizes AGPR cold reads 4x).
#define SLICE(s, HB) { \
    const F4 hv0 = *(const F4*)((HB) + 0*HP1 + 4*(s)); \
    const F4 hv1 = *(const F4*)((HB) + 1*HP1 + 4*(s)); \
    const F4 hv2 = *(const F4*)((HB) + 2*HP1 + 4*(s)); \
    const F4 hv3 = *(const F4*)((HB) + 3*HP1 + 4*(s)); \
    FMA4(a00, wa##s, hv0) FMA4(a01, wb##s, hv0) FMA4(a02, wc##s, hv0) FMA4(a03, wd##s, hv0) \
    FMA4(a10, wa##s, hv1) FMA4(a11, wb##s, hv1) FMA4(a12, wc##s, hv1) FMA4(a13, wd##s, hv1) \
    FMA4(a20, wa##s, hv2) FMA4(a21, wb##s, hv2) FMA4(a22, wc##s, hv2) FMA4(a23, wd##s, hv2) \
    FMA4(a30, wa##s, hv3) FMA4(a31, wb##s, hv3) FMA4(a32, wc##s, hv3) FMA4(a33, wd##s, hv3) }

#define BXOR(OP) \
    a00=OP(a00); a01=OP(a01); a02=OP(a02); a03=OP(a03); \
    a10=OP(a10); a11=OP(a11); a12=OP(a12); a13=OP(a13); \
    a20=OP(a20); a21=OP(a21); a22=OP(a22); a23=OP(a23); \
    a30=OP(a30); a31=OP(a31); a32=OP(a32); a33=OP(a33);

#define PW(P0, P1, P2, P3, CL, WP) { \
    const float ig = fsig(bs0 + P0), fg = fsig(bs1 + P1); \
    const float gg = ftanh(bs2 + P2), og = fsig(bs3 + P3); \
    const float cc = fg * CL + ig * gg; CL = cc; \
    *(WP) = og * ftanh(cc); }

// L1: 6 slices (24 cols), pair butterfly xor1, own batches 2*sub+{0,1}
#define L1BODY(HB, WR) { \
    ACC16 \
    SLICE(0, HB) SLICE(1, HB) SLICE(2, HB) SLICE(3, HB) SLICE(4, HB) SLICE(5, HB) \
    BXOR(QX1) \
    { const float p0 = sub ? a20 : a00, p1 = sub ? a21 : a01; \
      const float p2 = sub ? a22 : a02, p3 = sub ? a23 : a03; \
      PW(p0, p1, p2, p3, cl0, WR) } \
    { const float p0 = sub ? a30 : a10, p1 = sub ? a31 : a11; \
      const float p2 = sub ? a32 : a12, p3 = sub ? a33 : a13; \
      PW(p0, p1, p2, p3, cl1, (WR) + HP1) } }

// L2: 5 slices (20 cols), quad butterfly xor1+xor2, own batch sub
#define SEL4(g) ({ const float v01_ = (sub & 1) ? a1##g : a0##g; \
                   const float v23_ = (sub & 1) ? a3##g : a2##g; \
                   (sub & 2) ? v23_ : v01_; })
#define L2BODY(HB, WR) { \
    ACC16 \
    SLICE(0, HB) SLICE(1, HB) SLICE(2, HB) SLICE(3, HB) SLICE(4, HB) \
    BXOR(QX1) BXOR(QX2) \
    const float p0 = SEL4(0), p1 = SEL4(1), p2 = SEL4(2), p3 = SEL4(3); \
    PW(p0, p1, p2, p3, cl0, WR) }

// One pipeline iteration. PF load issued FIRST (issue-early / write-late).
#define ITER(L1GO, L2GO, TNX, HB, WR, PW_) { \
    const int tnx_ = (TNX); \
    const bool pfgo_ = isPF && (tnx_ < TT); \
    float pfv_ = 0.0f; \
    if (pfgo_) pfv_ = xg[(size_t)tnx_ * NI]; \
    if (isL1) { if (L1GO) L1BODY(HB, WR) } \
    else if (isL2) { if (L2GO) L2BODY(HB, WR) } \
    if (pfgo_) *(PW_) = pfv_; \
    __syncthreads(); }

// Role layout (8 waves / 512 threads), skewed pipeline, one barrier/iter:
//   tid   0..151 : L1. pair k=tid>>1: u=k%38, b0i=(k/38)*4; sub=tid&1 ->
//                  24-col slice of augmented 48-col row. 96 weight floats.
//                  k-outer: 6 slices x (4 ds_read + 64 FMA). DPP xor1.
//                  Owns batches b0i+2sub+{0,1}.
//   tid 152..199 : x prefetch, 1 element each, into h1buf[cur] x-cols.
//   tid 200..207 : idle.
//   tid 208..511 : L2. m=tid-208: quad k=m>>2 (u=k%38, b0i), sub=m&3 ->
//                  side=sub>>1 (0: Wih1/h1(i-1), 1: Whh1/h2(i-2)), half=sub&1
//                  (20-col slice). 80 weight floats. k-outer: 5 slices.
//                  DPP xor1+xor2. Owns batch b0i+sub.
// Iter i: L1 -> h1(i), L2 -> h2(i-1). Loop i=0..TT. Final h2(TT-1) in h2buf[1].
//
// LDS PAD (R6-verified lever): 88.5 KB static LDS -> 1 block/CU -> 2 waves/EU
// register regime. R6 post-mortem: weights overflow the 88 arch VGPRs into
// AGPR cold storage; round-major order re-read each weight 4x/step -> ~3x
// VALU inflation (8.8k vs 3k wave-insts/CU/step). k-outer makes each weight
// AGPR-read once/step; DPP butterflies take shuffles off the LDS pipe.

__global__ __launch_bounds__(BLK, 2) void lstm2_kernel(
    const float* __restrict__ x,
    const float* __restrict__ Wih0, const float* __restrict__ Whh0, const float* __restrict__ b0,
    const float* __restrict__ Wih1, const float* __restrict__ Whh1, const float* __restrict__ b1,
    const float* __restrict__ Wc,   const float* __restrict__ bc,
    float* __restrict__ out)
{
    __shared__ __align__(16) float h1buf[2][NB][HP1];   // 3072 B
    __shared__ __align__(16) float h2buf[2][NB][HP2];   // 3072 B
    __shared__ float ldspad[20608];                     // 82432 B -> total 88576 B

    const int tid   = threadIdx.x;
    const int bbase = blockIdx.x * NB;

    // keep the pad alive (runtime-false guard; inputs are ~N(0,0.16))
    if (bc[0] > 3.0e38f) ldspad[tid] = x[tid];

    // zero both state buffers (pads + x slots start at 0)
    for (int idx = tid; idx < 2 * NB * HP1; idx += BLK) (&h1buf[0][0][0])[idx] = 0.0f;
    for (int idx = tid; idx < 2 * NB * HP2; idx += BLK) (&h2buf[0][0][0])[idx] = 0.0f;
    __syncthreads();
    // x(0) into slot 1 x-cols (iter 0 reads prv=1)
    if (tid < NB * NI) {
        const int b = tid / NI, j = tid % NI;
        h1buf[1][b][XOFF + j] = x[(size_t)(bbase + b) * TT * NI + j];
    }

    const bool isL1 = (tid < 152);
    const bool isPF = (tid >= 152) && (tid < 152 + NB * NI);
    const bool isL2 = (tid >= 208);

    int sub = 0, u = 0, b0i = 0;
    if (isL1)      { const int k = tid >> 1;  sub = tid & 1; u = k % NH; b0i = (k / NH) * 4; }
    else if (isL2) { const int m = tid - 208; const int k = m >> 2;
                     sub = m & 3; u = k % NH; b0i = (k / NH) * 4; }

    // ---- ONE shared named weight set: 24 F4 (L1 uses all 6 slices, L2 first 5) ----
    F4 wa0,wa1,wa2,wa3,wa4,wa5, wb0,wb1,wb2,wb3,wb4,wb5;
    F4 wc0,wc1,wc2,wc3,wc4,wc5, wd0,wd1,wd2,wd3,wd4,wd5;
    {
        const F4 z = {0.f,0.f,0.f,0.f};
        wa0=z;wa1=z;wa2=z;wa3=z;wa4=z;wa5=z; wb0=z;wb1=z;wb2=z;wb3=z;wb4=z;wb5=z;
        wc0=z;wc1=z;wc2=z;wc3=z;wc4=z;wc5=z; wd0=z;wd1=z;wd2=z;wd3=z;wd4=z;wd5=z;
    }
    float bs0=0.f, bs1=0.f, bs2=0.f, bs3=0.f;

    const float *hb0 = nullptr, *hb1 = nullptr, *xg = nullptr;
    float *wr0 = nullptr, *wr1 = nullptr, *pw0 = nullptr, *pw1 = nullptr;

    if (isL1) {
        const int c = 24 * sub;
        wa0=aug4(Whh0,Wih0,u+0*NH,c);   wa1=aug4(Whh0,Wih0,u+0*NH,c+4);
        wa2=aug4(Whh0,Wih0,u+0*NH,c+8); wa3=aug4(Whh0,Wih0,u+0*NH,c+12);
        wa4=aug4(Whh0,Wih0,u+0*NH,c+16);wa5=aug4(Whh0,Wih0,u+0*NH,c+20);
        wb0=aug4(Whh0,Wih0,u+1*NH,c);   wb1=aug4(Whh0,Wih0,u+1*NH,c+4);
        wb2=aug4(Whh0,Wih0,u+1*NH,c+8); wb3=aug4(Whh0,Wih0,u+1*NH,c+12);
        wb4=aug4(Whh0,Wih0,u+1*NH,c+16);wb5=aug4(Whh0,Wih0,u+1*NH,c+20);
        wc0=aug4(Whh0,Wih0,u+2*NH,c);   wc1=aug4(Whh0,Wih0,u+2*NH,c+4);
        wc2=aug4(Whh0,Wih0,u+2*NH,c+8); wc3=aug4(Whh0,Wih0,u+2*NH,c+12);
        wc4=aug4(Whh0,Wih0,u+2*NH,c+16);wc5=aug4(Whh0,Wih0,u+2*NH,c+20);
        wd0=aug4(Whh0,Wih0,u+3*NH,c);   wd1=aug4(Whh0,Wih0,u+3*NH,c+4);
        wd2=aug4(Whh0,Wih0,u+3*NH,c+8); wd3=aug4(Whh0,Wih0,u+3*NH,c+12);
        wd4=aug4(Whh0,Wih0,u+3*NH,c+16);wd5=aug4(Whh0,Wih0,u+3*NH,c+20);
        bs0=b0[u]; bs1=b0[u+NH]; bs2=b0[u+2*NH]; bs3=b0[u+3*NH];
        hb0 = &h1buf[1][b0i][c];            // parity0 reads PRV=1
        hb1 = &h1buf[0][b0i][c];
        wr0 = &h1buf[0][b0i + 2*sub][u];    // parity0 writes CUR=0 (2 adjacent rows)
        wr1 = &h1buf[1][b0i + 2*sub][u];
    } else if (isL2) {
        const int side = sub >> 1, half = sub & 1;
        const float* Wm = side ? Whh1 : Wih1;
        const int c = 20 * half;
        wa0=ldp4(Wm,u+0*NH,c); wa1=ldp4(Wm,u+0*NH,c+4); wa2=ldp4(Wm,u+0*NH,c+8);
        wa3=ldp4(Wm,u+0*NH,c+12); wa4=ldp4(Wm,u+0*NH,c+16);
        wb0=ldp4(Wm,u+1*NH,c); wb1=ldp4(Wm,u+1*NH,c+4); wb2=ldp4(Wm,u+1*NH,c+8);
        wb3=ldp4(Wm,u+1*NH,c+12); wb4=ldp4(Wm,u+1*NH,c+16);
        wc0=ldp4(Wm,u+2*NH,c); wc1=ldp4(Wm,u+2*NH,c+4); wc2=ldp4(Wm,u+2*NH,c+8);
        wc3=ldp4(Wm,u+2*NH,c+12); wc4=ldp4(Wm,u+2*NH,c+16);
        wd0=ldp4(Wm,u+3*NH,c); wd1=ldp4(Wm,u+3*NH,c+4); wd2=ldp4(Wm,u+3*NH,c+8);
        wd3=ldp4(Wm,u+3*NH,c+12); wd4=ldp4(Wm,u+3*NH,c+16);
        bs0=b1[u]; bs1=b1[u+NH]; bs2=b1[u+2*NH]; bs3=b1[u+3*NH];
        hb0 = side ? &h2buf[0][b0i][c] : &h1buf[1][b0i][c];   // parity0: h2(i-2) / h1(i-1)
        hb1 = side ? &h2buf[1][b0i][c] : &h1buf[0][b0i][c];
        wr0 = &h2buf[1][b0i + sub][u];      // parity0 writes PRV=1
        wr1 = &h2buf[0][b0i + sub][u];
    } else if (isPF) {
        const int e = tid - 152, b = e / NI, j = e % NI;
        xg  = x + (size_t)(bbase + b) * TT * NI + j;
        pw0 = &h1buf[0][b][XOFF + j];       // parity0 writes CUR=0 x-cols
        pw1 = &h1buf[1][b][XOFF + j];
    }

    float cl0 = 0.0f, cl1 = 0.0f;   // cell states (L1: 2 batches; L2: cl0)

    __syncthreads();

    // iter 0: parity0 (CUR=0, PRV=1): L1 only; PF x(1) -> h1buf[0]
    ITER(true, false, 1, hb0, wr0, pw0)

    // pairs (i, i+1) for i = 1,3,...,1023  -> iterations 1..1024
    #pragma unroll 1
    for (int i = 1; i < TT; i += 2) {
        ITER(true, true, i + 1, hb1, wr1, pw1)            // parity 1
        ITER(i + 1 < TT, true, i + 2, hb0, wr0, pw0)      // parity 0
    }

    // epilogue: out = h2(TT-1) @ Wc.T + bc ; final h2 in h2buf[1]
    if (tid < NB * NCLS) {
        const int b = tid >> 3, c = tid & 7;
        float acc = bc[c];
        #pragma unroll
        for (int k = 0; k < NH; ++k) acc += Wc[c * NH + k] * h2buf[1][b][k];
        out[(size_t)(bbase + b) * NCLS + c] = acc;
    }
    if (bc[0] > 3.0e38f) out[tid] = ldspad[BLK - tid];
}

extern "C" void kernel_launch(void* const* d_in, const int* in_sizes, int n_in,
                              void* d_out, int out_size, void* d_ws, size_t ws_size,
                              hipStream_t stream) {
    const float* x    = (const float*)d_in[0];
    const float* Wih0 = (const float*)d_in[1];
    const float* Whh0 = (const float*)d_in[2];
    const float* b0   = (const float*)d_in[3];
    const float* Wih1 = (const float*)d_in[4];
    const float* Whh1 = (const float*)d_in[5];
    const float* b1   = (const float*)d_in[6];
    const float* Wc   = (const float*)d_in[7];
    const float* bc   = (const float*)d_in[8];
    float* out = (float*)d_out;

    dim3 grid(BATCH / NB);
    dim3 block(BLK);
    hipLaunchKernelGGL(lstm2_kernel, grid, block, 0, stream,
                       x, Wih0, Whh0, b0, Wih1, Whh1, b1, Wc, bc, out);
}